// Round 6
// baseline (589.700 us; speedup 1.0000x reference)
//
#include <hip/hip_runtime.h>
#include <math.h>

#define N_LOC 16384
#define W 128
#define B_SZ 64
#define TOTAL_OUT 390   // 3*W + 6
#define NBLK 512

__device__ __forceinline__ float dot4(float4 a, float4 b) {
    return a.x * b.x + a.y * b.y + a.z * b.z + a.w * b.w;
}
__device__ __forceinline__ float softplus_f(float x) {
    return fmaxf(x, 0.0f) + log1pf(expf(-fabsf(x)));
}
__device__ __forceinline__ float wave_reduce_sum(float v) {
#pragma unroll
    for (int off = 32; off >= 1; off >>= 1) v += __shfl_xor(v, off);
    return v;
}

// ---------------------------------------------------------------------------
// Hand-rolled grid barrier. One fresh counter per barrier point (memset to 0
// by kernel_launch each call). Agent-scope ACQ_REL add publishes this XCD's
// dirty L2 lines (buffer_wbl2); spin acquire-load invalidates stale lines.
// Safe because hipLaunchCooperativeKernel guarantees all 512 blocks resident.
// ---------------------------------------------------------------------------
__device__ __forceinline__ void grid_barrier(unsigned* cnt) {
    __syncthreads();
    if (threadIdx.x == 0) {
        __hip_atomic_fetch_add(cnt, 1u, __ATOMIC_ACQ_REL, __HIP_MEMORY_SCOPE_AGENT);
        while (__hip_atomic_load(cnt, __ATOMIC_ACQUIRE, __HIP_MEMORY_SCOPE_AGENT)
               < NBLK) {
            __builtin_amdgcn_s_sleep(2);
        }
    }
    __syncthreads();
}

// ---------------------------------------------------------------------------
// Phase A (blocks 0..63, one per b): raw[b][:] = cs[b].fc_w.T + fc_b, then all
// activations for row b. keyb = beta*key/||key||; beta doubles as softmax max.
// ---------------------------------------------------------------------------
__device__ void phaseA(int blk, int t,
                       const float* __restrict__ cs, const float* __restrict__ fcw,
                       const float* __restrict__ fcb,
                       float* __restrict__ raw, float* __restrict__ keyb,
                       float* __restrict__ erase, float* __restrict__ addv,
                       float* __restrict__ gate, float* __restrict__ shift,
                       float* __restrict__ gamma, float* __restrict__ beta_out) {
    __shared__ float4 cs4s[256];
    __shared__ float rA[2];
    const int b = blk;
    cs4s[t] = reinterpret_cast<const float4*>(cs)[b * 256 + t];
    __syncthreads();
    const int lane = t & 63, wv = t >> 6;
    const float4* fcw4 = reinterpret_cast<const float4*>(fcw);
    for (int o = wv; o < TOTAL_OUT; o += 4) {
        float acc = dot4(cs4s[0 * 64 + lane], fcw4[o * 256 + 0 * 64 + lane]);
        acc += dot4(cs4s[1 * 64 + lane], fcw4[o * 256 + 1 * 64 + lane]);
        acc += dot4(cs4s[2 * 64 + lane], fcw4[o * 256 + 2 * 64 + lane]);
        acc += dot4(cs4s[3 * 64 + lane], fcw4[o * 256 + 3 * 64 + lane]);
        acc = wave_reduce_sum(acc);
        if (lane == 0) raw[b * TOTAL_OUT + o] = acc + fcb[o];
    }
    __syncthreads();     // raw row b visible block-wide
    const float* rb = raw + b * TOTAL_OUT;
    float key = (t < 128) ? rb[t] : 0.0f;
    float ss = wave_reduce_sum(key * key);
    if (t == 0 || t == 64) rA[t >> 6] = ss;
    __syncthreads();
    if (t < 128) {
        float tot = rA[0] + rA[1];
        float inv = 1.0f / fmaxf(sqrtf(tot), 1e-12f);
        float beta = softplus_f(rb[W]);
        keyb[b * W + t] = beta * key * inv;
        erase[b * W + t] = 1.0f / (1.0f + expf(-rb[W + 6 + t]));
        addv[b * W + t] = tanhf(rb[2 * W + 6 + t]);
        if (t == 0) {
            gate[b] = 1.0f / (1.0f + expf(-rb[W + 1]));
            gamma[b] = softplus_f(rb[W + 5]) + 1.0f;
            beta_out[b] = beta;
            float s0 = rb[W + 2], s1 = rb[W + 3], s2 = rb[W + 4];
            float m = fmaxf(s0, fmaxf(s1, s2));
            float e0 = expf(s0 - m), e1 = expf(s1 - m), e2 = expf(s2 - m);
            float si = 1.0f / (e0 + e1 + e2);
            shift[b * 3 + 0] = e0 * si;
            shift[b * 3 + 1] = e1 * si;
            shift[b * 3 + 2] = e2 * si;
        }
    }
}

// Blocks 64..511 warm L2 with their own phase-B mem rows while phase A runs.
__device__ void prefetchB(int blk, int t, const float* __restrict__ mem) {
    const float4* mr = reinterpret_cast<const float4*>(mem) + (size_t)blk * 32 * 32;
#pragma unroll
    for (int i = 0; i < 4; i++) {
        float4 v = mr[t + 256 * i];
        asm volatile("" :: "v"(v.x), "v"(v.y), "v"(v.z), "v"(v.w));
    }
}

// ---------------------------------------------------------------------------
// Phase B (512 blocks, 32 n each): e[b][n] = exp(cosine*beta - beta), plus
// per-(b, 32n) partial sums. keyb broadcast from LDS; mem rows from global.
// ---------------------------------------------------------------------------
__device__ void phaseB(int blk, int t,
                       const float* __restrict__ mem, const float* __restrict__ keyb,
                       const float* __restrict__ beta_,
                       float* __restrict__ e_buf, float* __restrict__ partialS) {
    __shared__ float4 kb4[B_SZ][32];   // 32 KB
    const float4* kg = reinterpret_cast<const float4*>(keyb);
    float4* kbp = &kb4[0][0];
#pragma unroll
    for (int i = 0; i < 8; i++) kbp[t + 256 * i] = kg[t + 256 * i];
    __syncthreads();

    const int nl = t & 31;
    const int n = blk * 32 + nl;
    const int bg = t >> 5;             // 0..7 -> b = bg*8 + bi
    const float4* mrow = reinterpret_cast<const float4*>(mem) + (size_t)n * 32;

    float acc[8];
#pragma unroll
    for (int i = 0; i < 8; i++) acc[i] = 0.0f;
    float nrm = 0.0f;
#pragma unroll 8
    for (int k4 = 0; k4 < 32; k4++) {
        float4 mv = mrow[k4];
        nrm += dot4(mv, mv);
#pragma unroll
        for (int bi = 0; bi < 8; bi++)
            acc[bi] += dot4(kb4[bg * 8 + bi][k4], mv);
    }
    const float r = 1.0f / fmaxf(sqrtf(nrm), 1e-12f);
    float ev[8];
#pragma unroll
    for (int bi = 0; bi < 8; bi++) {
        const int b = bg * 8 + bi;
        float e = __expf(acc[bi] * r - beta_[b]);
        ev[bi] = e;
        e_buf[(size_t)b * N_LOC + n] = e;
    }
#pragma unroll
    for (int bi = 0; bi < 8; bi++) {
        float v = ev[bi];
#pragma unroll
        for (int off = 16; off >= 1; off >>= 1) v += __shfl_xor(v, off);
        ev[bi] = v;
    }
    if (nl == 0) {
#pragma unroll
        for (int bi = 0; bi < 8; bi++)
            partialS[(bg * 8 + bi) * 512 + blk] = ev[bi];
    }
}

// ---------------------------------------------------------------------------
// Phase C (512 blocks = 64 b x 8 chunks of 2048): S-reduce (fixed order),
// gate-mix, circular 3-tap shift (scalar halo), sharpen, write unnormalized p
// + partialP[b][8].
// ---------------------------------------------------------------------------
__device__ void phaseC(int blk, int t,
                       const float* __restrict__ e_buf, const float* __restrict__ wprev,
                       const float* __restrict__ partialS,
                       const float* __restrict__ gate_, const float* __restrict__ shift_,
                       const float* __restrict__ gamma_,
                       float* __restrict__ p_buf, float* __restrict__ partialP) {
    __shared__ float rC[4];
    const int b = blk >> 3, c = blk & 7;
    const float* ps = partialS + b * 512;
    float sv = ps[t] + ps[t + 256];
    sv = wave_reduce_sum(sv);
    if ((t & 63) == 0) rC[t >> 6] = sv;
    __syncthreads();
    const float S = rC[0] + rC[1] + rC[2] + rC[3];

    const float gate = gate_[b];
    const float ga = gate / S;
    const float og = 1.0f - gate;
    const float gm = gamma_[b];
    const float sh0 = shift_[b * 3 + 0];
    const float sh1 = shift_[b * 3 + 1];
    const float sh2 = shift_[b * 3 + 2];

    const float* erow = e_buf + (size_t)b * N_LOC;
    const float* wrow = wprev + (size_t)b * N_LOC;
    const int nb = c * 2048 + 8 * t;

    float4 e0 = *reinterpret_cast<const float4*>(erow + nb);
    float4 e1 = *reinterpret_cast<const float4*>(erow + nb + 4);
    float4 w0 = *reinterpret_cast<const float4*>(wrow + nb);
    float4 w1 = *reinterpret_cast<const float4*>(wrow + nb + 4);
    const int nm1 = (nb + N_LOC - 1) & (N_LOC - 1);
    const int np8 = (nb + 8) & (N_LOC - 1);

    float g[10];
    g[0] = ga * erow[nm1] + og * wrow[nm1];
    g[1] = ga * e0.x + og * w0.x;
    g[2] = ga * e0.y + og * w0.y;
    g[3] = ga * e0.z + og * w0.z;
    g[4] = ga * e0.w + og * w0.w;
    g[5] = ga * e1.x + og * w1.x;
    g[6] = ga * e1.y + og * w1.y;
    g[7] = ga * e1.z + og * w1.z;
    g[8] = ga * e1.w + og * w1.w;
    g[9] = ga * erow[np8] + og * wrow[np8];

    float p[8];
    float sp = 0.0f;
#pragma unroll
    for (int j = 0; j < 8; j++) {
        float x = fmaxf(sh0 * g[j] + sh1 * g[j + 1] + sh2 * g[j + 2], 1e-9f);
        p[j] = exp2f(gm * __log2f(x));
        sp += p[j];
    }
    *reinterpret_cast<float4*>(p_buf + (size_t)b * N_LOC + nb) =
        make_float4(p[0], p[1], p[2], p[3]);
    *reinterpret_cast<float4*>(p_buf + (size_t)b * N_LOC + nb + 4) =
        make_float4(p[4], p[5], p[6], p[7]);

    sp = wave_reduce_sum(sp);
    __syncthreads();
    if ((t & 63) == 0) rC[t >> 6] = sp;
    __syncthreads();
    if (t == 0) partialP[b * 8 + c] = rC[0] + rC[1] + rC[2] + rC[3];
}

// ---------------------------------------------------------------------------
// Phase D (512 blocks, 32 n each): invb[b] = 1/(S2+eps) (fixed order);
// accumulate erase/add outer products with invb & 1/64 folded in; memory
// update; then in-place normalize p -> w_new for this block's n-range.
// ---------------------------------------------------------------------------
__device__ void phaseD(int blk, int t,
                       const float* __restrict__ mem, const float* __restrict__ erase,
                       const float* __restrict__ addv, const float* __restrict__ partialP,
                       float* __restrict__ p_buf, float* __restrict__ outmem) {
    __shared__ float invb[B_SZ];
    if (t < B_SZ) {
        const float* pp = partialP + t * 8;
        float s = 0.0f;
#pragma unroll
        for (int j = 0; j < 8; j++) s += pp[j];
        invb[t] = 1.0f / (s + 1e-9f);
    }
    __syncthreads();

    const int w = t & 127;
    const int nh = t >> 7;
    const int nb = blk * 32;
    const int nbase = nb + nh * 16;

    float ae[16], aa[16];
#pragma unroll
    for (int i = 0; i < 16; i++) { ae[i] = 0.0f; aa[i] = 0.0f; }

    for (int b = 0; b < B_SZ; b++) {
        const float ib = invb[b] * (1.0f / 64.0f);
        const float wei = erase[b * W + w] * ib;
        const float wai = addv[b * W + w] * ib;
        const float4* pr4 =
            reinterpret_cast<const float4*>(p_buf + (size_t)b * N_LOC + nbase);
#pragma unroll
        for (int i4 = 0; i4 < 4; i4++) {
            float4 v = pr4[i4];
            ae[i4 * 4 + 0] += v.x * wei; aa[i4 * 4 + 0] += v.x * wai;
            ae[i4 * 4 + 1] += v.y * wei; aa[i4 * 4 + 1] += v.y * wai;
            ae[i4 * 4 + 2] += v.z * wei; aa[i4 * 4 + 2] += v.z * wai;
            ae[i4 * 4 + 3] += v.w * wei; aa[i4 * 4 + 3] += v.w * wai;
        }
    }
#pragma unroll
    for (int i = 0; i < 16; i++) {
        const int n = nbase + i;
        float mv = mem[(size_t)n * W + w];
        outmem[(size_t)n * W + w] = mv * (1.0f - ae[i]) + aa[i];
    }
    __syncthreads();   // all accumulation reads of p done before overwrite
    const int b8 = t >> 5, nl = t & 31;
#pragma unroll
    for (int bi = 0; bi < 8; bi++) {
        const int b = bi * 8 + b8;
        const size_t idx = (size_t)b * N_LOC + nb + nl;
        p_buf[idx] *= invb[b];
    }
}

// ---------------------------------------------------------------------------
// Fused kernel: 512 blocks x 256 threads, 3 hand-rolled grid barriers.
// Launched cooperatively (co-residency guarantee), but uses custom barriers
// instead of cg::sync (measured ~83 us/sync on gfx950 -> replaced).
// ---------------------------------------------------------------------------
__global__ __launch_bounds__(256, 2) void ntm_fused(
        const float* cs, const float* mem, const float* wprev,
        const float* fcw, const float* fcb,
        float* raw, float* keyb, float* erase, float* addv,
        float* gate, float* shift, float* gamma, float* beta,
        float* partialS, float* partialP,
        float* p_buf, float* emem, unsigned* bars) {
    const int t = threadIdx.x;
    const int blk = blockIdx.x;
    if (blk < B_SZ) {
        phaseA(blk, t, cs, fcw, fcb, raw, keyb, erase, addv, gate, shift, gamma,
               beta);
    } else {
        prefetchB(blk, t, mem);
    }
    grid_barrier(bars + 0);
    phaseB(blk, t, mem, keyb, beta, emem, partialS);
    grid_barrier(bars + 1);
    phaseC(blk, t, emem, wprev, partialS, gate, shift, gamma, p_buf, partialP);
    grid_barrier(bars + 2);
    phaseD(blk, t, mem, erase, addv, partialP, p_buf, emem);
}

// Fallback path: same phases as 4 separate kernels (no barriers needed).
__global__ __launch_bounds__(256) void kA(const float* cs, const float* fcw,
                                          const float* fcb, float* raw, float* keyb,
                                          float* erase, float* addv, float* gate,
                                          float* shift, float* gamma, float* beta) {
    if (blockIdx.x < B_SZ)
        phaseA(blockIdx.x, threadIdx.x, cs, fcw, fcb, raw, keyb, erase, addv, gate,
               shift, gamma, beta);
}
__global__ __launch_bounds__(256) void kB(const float* mem, const float* keyb,
                                          const float* beta, float* e_buf,
                                          float* partialS) {
    phaseB(blockIdx.x, threadIdx.x, mem, keyb, beta, e_buf, partialS);
}
__global__ __launch_bounds__(256) void kC(const float* e_buf, const float* wprev,
                                          const float* partialS, const float* gate,
                                          const float* shift, const float* gamma,
                                          float* p_buf, float* partialP) {
    phaseC(blockIdx.x, threadIdx.x, e_buf, wprev, partialS, gate, shift, gamma,
           p_buf, partialP);
}
__global__ __launch_bounds__(256) void kD(const float* mem, const float* erase,
                                          const float* addv, const float* partialP,
                                          float* p_buf, float* outmem) {
    phaseD(blockIdx.x, threadIdx.x, mem, erase, addv, partialP, p_buf, outmem);
}

// ---------------------------------------------------------------------------
extern "C" void kernel_launch(void* const* d_in, const int* in_sizes, int n_in,
                              void* d_out, int out_size, void* d_ws, size_t ws_size,
                              hipStream_t stream) {
    const float* cs    = (const float*)d_in[0];   // (64, 1024)
    const float* mem   = (const float*)d_in[1];   // (16384, 128)
    const float* wprev = (const float*)d_in[2];   // (64, 16384)
    const float* fcw   = (const float*)d_in[3];   // (390, 1024)
    const float* fcb   = (const float*)d_in[4];   // (390,)

    float* out = (float*)d_out;
    float* p_buf = out;                                  // (64,16384): p -> w_new
    float* emem = out + (size_t)B_SZ * N_LOC;            // e_buf, then new_memory

    float* wsf = (float*)d_ws;
    float* raw      = wsf;               // 24960
    float* keyb     = raw + 24960;       // 8192 (16B aligned)
    float* erase    = keyb + 8192;       // 8192
    float* addv     = erase + 8192;      // 8192
    float* gate     = addv + 8192;       // 64
    float* shift    = gate + 64;         // 192
    float* gamma    = shift + 192;       // 64
    float* beta     = gamma + 64;        // 64
    float* partialS = beta + 64;         // 64*512 (16B aligned)
    float* partialP = partialS + 32768;  // 64*8 = 512
    unsigned* bars  = (unsigned*)(partialP + 512);   // 3 barrier counters

    hipMemsetAsync(bars, 0, 3 * sizeof(unsigned), stream);

    void* args[] = {
        (void*)&cs, (void*)&mem, (void*)&wprev, (void*)&fcw, (void*)&fcb,
        (void*)&raw, (void*)&keyb, (void*)&erase, (void*)&addv,
        (void*)&gate, (void*)&shift, (void*)&gamma, (void*)&beta,
        (void*)&partialS, (void*)&partialP, (void*)&p_buf, (void*)&emem,
        (void*)&bars
    };
    dim3 grid(NBLK), block(256);
    hipError_t err = hipLaunchCooperativeKernel((const void*)ntm_fused, grid, block,
                                                args, 0, stream);
    if (err != hipSuccess) {
        // Fallback: 4 conventional launches with identical semantics.
        kA<<<64, 256, 0, stream>>>(cs, fcw, fcb, raw, keyb, erase, addv, gate,
                                   shift, gamma, beta);
        kB<<<512, 256, 0, stream>>>(mem, keyb, beta, emem, partialS);
        kC<<<512, 256, 0, stream>>>(emem, wprev, partialS, gate, shift, gamma,
                                    p_buf, partialP);
        kD<<<512, 256, 0, stream>>>(mem, erase, addv, partialP, p_buf, emem);
    }
}

// Round 7
// 204.506 us; speedup vs baseline: 2.8835x; 2.8835x over previous
//
#include <hip/hip_runtime.h>
#include <math.h>

#define N_LOC 16384
#define W 128
#define B_SZ 64
#define TOTAL_OUT 390   // 3*W + 6
#define NBLK 512

__device__ __forceinline__ float dot4(float4 a, float4 b) {
    return a.x * b.x + a.y * b.y + a.z * b.z + a.w * b.w;
}
__device__ __forceinline__ float softplus_f(float x) {
    return fmaxf(x, 0.0f) + log1pf(expf(-fabsf(x)));
}
__device__ __forceinline__ float wave_reduce_sum(float v) {
#pragma unroll
    for (int off = 32; off >= 1; off >>= 1) v += __shfl_xor(v, off);
    return v;
}

// ---------------------------------------------------------------------------
// Grid barrier v3 — no atomic RMWs (512 serialized cross-XCD RMWs on one line
// cost ~82us ~= cg::sync's measured 83us/barrier).
//   arrival: per-block release-STORE on the block's OWN cacheline (parallel)
//   aggregate: block 0's 256 threads sweep all 512 flags (2 loads/thread)
//   publish: one gen flag; others poll that single line (read-only, 0.43us
//            interval) -- reads don't serialize like RMWs.
// flags[] and gen are memset to 0 at the start of every call (in-graph).
// Visibility: __syncthreads drains vmcnt (writes reach L2); one thread's
// __threadfence (agent scope) emits the L2 writeback/invalidate pair that
// crosses the non-coherent per-XCD L2s.
// ---------------------------------------------------------------------------
__device__ __forceinline__ void grid_barrier(unsigned* flags, unsigned* gen,
                                             unsigned k) {
    const int t = threadIdx.x;
    __syncthreads();
    if (t == 0) {
        __threadfence();
        __hip_atomic_store(flags + (size_t)blockIdx.x * 16, k,
                           __ATOMIC_RELAXED, __HIP_MEMORY_SCOPE_AGENT);
    }
    if (blockIdx.x == 0) {
        for (;;) {
            unsigned a = __hip_atomic_load(flags + (size_t)t * 16,
                                           __ATOMIC_RELAXED, __HIP_MEMORY_SCOPE_AGENT);
            unsigned b = __hip_atomic_load(flags + (size_t)(t + 256) * 16,
                                           __ATOMIC_RELAXED, __HIP_MEMORY_SCOPE_AGENT);
            if (a >= k && b >= k) break;
            __builtin_amdgcn_s_sleep(4);
        }
        __syncthreads();
        if (t == 0) {
            __threadfence();
            __hip_atomic_store(gen, k, __ATOMIC_RELAXED, __HIP_MEMORY_SCOPE_AGENT);
        }
    }
    if (t == 0) {
        while (__hip_atomic_load(gen, __ATOMIC_RELAXED, __HIP_MEMORY_SCOPE_AGENT) < k) {
            __builtin_amdgcn_s_sleep(16);
        }
        __threadfence();
    }
    __syncthreads();
}

// ---------------------------------------------------------------------------
// Phase A (blocks 0..63, one per b): raw[b][:] = cs[b].fc_w.T + fc_b, then all
// activations for row b. keyb = beta*key/||key||; beta doubles as softmax max.
// ---------------------------------------------------------------------------
__device__ void phaseA(int blk, int t,
                       const float* __restrict__ cs, const float* __restrict__ fcw,
                       const float* __restrict__ fcb,
                       float* __restrict__ raw, float* __restrict__ keyb,
                       float* __restrict__ erase, float* __restrict__ addv,
                       float* __restrict__ gate, float* __restrict__ shift,
                       float* __restrict__ gamma, float* __restrict__ beta_out) {
    __shared__ float4 cs4s[256];
    __shared__ float rA[2];
    const int b = blk;
    cs4s[t] = reinterpret_cast<const float4*>(cs)[b * 256 + t];
    __syncthreads();
    const int lane = t & 63, wv = t >> 6;
    const float4* fcw4 = reinterpret_cast<const float4*>(fcw);
    for (int o = wv; o < TOTAL_OUT; o += 4) {
        float acc = dot4(cs4s[0 * 64 + lane], fcw4[o * 256 + 0 * 64 + lane]);
        acc += dot4(cs4s[1 * 64 + lane], fcw4[o * 256 + 1 * 64 + lane]);
        acc += dot4(cs4s[2 * 64 + lane], fcw4[o * 256 + 2 * 64 + lane]);
        acc += dot4(cs4s[3 * 64 + lane], fcw4[o * 256 + 3 * 64 + lane]);
        acc = wave_reduce_sum(acc);
        if (lane == 0) raw[b * TOTAL_OUT + o] = acc + fcb[o];
    }
    __syncthreads();     // raw row b visible block-wide
    const float* rb = raw + b * TOTAL_OUT;
    float key = (t < 128) ? rb[t] : 0.0f;
    float ss = wave_reduce_sum(key * key);
    if (t == 0 || t == 64) rA[t >> 6] = ss;
    __syncthreads();
    if (t < 128) {
        float tot = rA[0] + rA[1];
        float inv = 1.0f / fmaxf(sqrtf(tot), 1e-12f);
        float beta = softplus_f(rb[W]);
        keyb[b * W + t] = beta * key * inv;
        erase[b * W + t] = 1.0f / (1.0f + expf(-rb[W + 6 + t]));
        addv[b * W + t] = tanhf(rb[2 * W + 6 + t]);
        if (t == 0) {
            gate[b] = 1.0f / (1.0f + expf(-rb[W + 1]));
            gamma[b] = softplus_f(rb[W + 5]) + 1.0f;
            beta_out[b] = beta;
            float s0 = rb[W + 2], s1 = rb[W + 3], s2 = rb[W + 4];
            float m = fmaxf(s0, fmaxf(s1, s2));
            float e0 = expf(s0 - m), e1 = expf(s1 - m), e2 = expf(s2 - m);
            float si = 1.0f / (e0 + e1 + e2);
            shift[b * 3 + 0] = e0 * si;
            shift[b * 3 + 1] = e1 * si;
            shift[b * 3 + 2] = e2 * si;
        }
    }
}

// Blocks 64..511 warm L2 with their own phase-B mem rows while phase A runs.
__device__ void prefetchB(int blk, int t, const float* __restrict__ mem) {
    const float4* mr = reinterpret_cast<const float4*>(mem) + (size_t)blk * 32 * 32;
#pragma unroll
    for (int i = 0; i < 4; i++) {
        float4 v = mr[t + 256 * i];
        asm volatile("" :: "v"(v.x), "v"(v.y), "v"(v.z), "v"(v.w));
    }
}

// ---------------------------------------------------------------------------
// Phase B (512 blocks, 32 n each): e[b][n] = exp(cosine*beta - beta), plus
// per-(b, 32n) partial sums. keyb broadcast from LDS; mem rows from global.
// ---------------------------------------------------------------------------
__device__ void phaseB(int blk, int t,
                       const float* __restrict__ mem, const float* __restrict__ keyb,
                       const float* __restrict__ beta_,
                       float* __restrict__ e_buf, float* __restrict__ partialS) {
    __shared__ float4 kb4[B_SZ][32];   // 32 KB
    const float4* kg = reinterpret_cast<const float4*>(keyb);
    float4* kbp = &kb4[0][0];
#pragma unroll
    for (int i = 0; i < 8; i++) kbp[t + 256 * i] = kg[t + 256 * i];
    __syncthreads();

    const int nl = t & 31;
    const int n = blk * 32 + nl;
    const int bg = t >> 5;             // 0..7 -> b = bg*8 + bi
    const float4* mrow = reinterpret_cast<const float4*>(mem) + (size_t)n * 32;

    float acc[8];
#pragma unroll
    for (int i = 0; i < 8; i++) acc[i] = 0.0f;
    float nrm = 0.0f;
#pragma unroll 8
    for (int k4 = 0; k4 < 32; k4++) {
        float4 mv = mrow[k4];
        nrm += dot4(mv, mv);
#pragma unroll
        for (int bi = 0; bi < 8; bi++)
            acc[bi] += dot4(kb4[bg * 8 + bi][k4], mv);
    }
    const float r = 1.0f / fmaxf(sqrtf(nrm), 1e-12f);
    float ev[8];
#pragma unroll
    for (int bi = 0; bi < 8; bi++) {
        const int b = bg * 8 + bi;
        float e = __expf(acc[bi] * r - beta_[b]);
        ev[bi] = e;
        e_buf[(size_t)b * N_LOC + n] = e;
    }
#pragma unroll
    for (int bi = 0; bi < 8; bi++) {
        float v = ev[bi];
#pragma unroll
        for (int off = 16; off >= 1; off >>= 1) v += __shfl_xor(v, off);
        ev[bi] = v;
    }
    if (nl == 0) {
#pragma unroll
        for (int bi = 0; bi < 8; bi++)
            partialS[(bg * 8 + bi) * 512 + blk] = ev[bi];
    }
}

// ---------------------------------------------------------------------------
// Phase C (512 blocks = 64 b x 8 chunks of 2048): S-reduce (fixed order),
// gate-mix, circular 3-tap shift (scalar halo), sharpen, write unnormalized p
// + partialP[b][8].
// ---------------------------------------------------------------------------
__device__ void phaseC(int blk, int t,
                       const float* __restrict__ e_buf, const float* __restrict__ wprev,
                       const float* __restrict__ partialS,
                       const float* __restrict__ gate_, const float* __restrict__ shift_,
                       const float* __restrict__ gamma_,
                       float* __restrict__ p_buf, float* __restrict__ partialP) {
    __shared__ float rC[4];
    const int b = blk >> 3, c = blk & 7;
    const float* ps = partialS + b * 512;
    float sv = ps[t] + ps[t + 256];
    sv = wave_reduce_sum(sv);
    if ((t & 63) == 0) rC[t >> 6] = sv;
    __syncthreads();
    const float S = rC[0] + rC[1] + rC[2] + rC[3];

    const float gate = gate_[b];
    const float ga = gate / S;
    const float og = 1.0f - gate;
    const float gm = gamma_[b];
    const float sh0 = shift_[b * 3 + 0];
    const float sh1 = shift_[b * 3 + 1];
    const float sh2 = shift_[b * 3 + 2];

    const float* erow = e_buf + (size_t)b * N_LOC;
    const float* wrow = wprev + (size_t)b * N_LOC;
    const int nb = c * 2048 + 8 * t;

    float4 e0 = *reinterpret_cast<const float4*>(erow + nb);
    float4 e1 = *reinterpret_cast<const float4*>(erow + nb + 4);
    float4 w0 = *reinterpret_cast<const float4*>(wrow + nb);
    float4 w1 = *reinterpret_cast<const float4*>(wrow + nb + 4);
    const int nm1 = (nb + N_LOC - 1) & (N_LOC - 1);
    const int np8 = (nb + 8) & (N_LOC - 1);

    float g[10];
    g[0] = ga * erow[nm1] + og * wrow[nm1];
    g[1] = ga * e0.x + og * w0.x;
    g[2] = ga * e0.y + og * w0.y;
    g[3] = ga * e0.z + og * w0.z;
    g[4] = ga * e0.w + og * w0.w;
    g[5] = ga * e1.x + og * w1.x;
    g[6] = ga * e1.y + og * w1.y;
    g[7] = ga * e1.z + og * w1.z;
    g[8] = ga * e1.w + og * w1.w;
    g[9] = ga * erow[np8] + og * wrow[np8];

    float p[8];
    float sp = 0.0f;
#pragma unroll
    for (int j = 0; j < 8; j++) {
        float x = fmaxf(sh0 * g[j] + sh1 * g[j + 1] + sh2 * g[j + 2], 1e-9f);
        p[j] = exp2f(gm * __log2f(x));
        sp += p[j];
    }
    *reinterpret_cast<float4*>(p_buf + (size_t)b * N_LOC + nb) =
        make_float4(p[0], p[1], p[2], p[3]);
    *reinterpret_cast<float4*>(p_buf + (size_t)b * N_LOC + nb + 4) =
        make_float4(p[4], p[5], p[6], p[7]);

    sp = wave_reduce_sum(sp);
    __syncthreads();
    if ((t & 63) == 0) rC[t >> 6] = sp;
    __syncthreads();
    if (t == 0) partialP[b * 8 + c] = rC[0] + rC[1] + rC[2] + rC[3];
}

// ---------------------------------------------------------------------------
// Phase D (512 blocks, 32 n each): invb[b] = 1/(S2+eps) (fixed order);
// accumulate erase/add outer products with invb & 1/64 folded in; memory
// update; then in-place normalize p -> w_new for this block's n-range.
// ---------------------------------------------------------------------------
__device__ void phaseD(int blk, int t,
                       const float* __restrict__ mem, const float* __restrict__ erase,
                       const float* __restrict__ addv, const float* __restrict__ partialP,
                       float* __restrict__ p_buf, float* __restrict__ outmem) {
    __shared__ float invb[B_SZ];
    if (t < B_SZ) {
        const float* pp = partialP + t * 8;
        float s = 0.0f;
#pragma unroll
        for (int j = 0; j < 8; j++) s += pp[j];
        invb[t] = 1.0f / (s + 1e-9f);
    }
    __syncthreads();

    const int w = t & 127;
    const int nh = t >> 7;
    const int nb = blk * 32;
    const int nbase = nb + nh * 16;

    float ae[16], aa[16];
#pragma unroll
    for (int i = 0; i < 16; i++) { ae[i] = 0.0f; aa[i] = 0.0f; }

    for (int b = 0; b < B_SZ; b++) {
        const float ib = invb[b] * (1.0f / 64.0f);
        const float wei = erase[b * W + w] * ib;
        const float wai = addv[b * W + w] * ib;
        const float4* pr4 =
            reinterpret_cast<const float4*>(p_buf + (size_t)b * N_LOC + nbase);
#pragma unroll
        for (int i4 = 0; i4 < 4; i4++) {
            float4 v = pr4[i4];
            ae[i4 * 4 + 0] += v.x * wei; aa[i4 * 4 + 0] += v.x * wai;
            ae[i4 * 4 + 1] += v.y * wei; aa[i4 * 4 + 1] += v.y * wai;
            ae[i4 * 4 + 2] += v.z * wei; aa[i4 * 4 + 2] += v.z * wai;
            ae[i4 * 4 + 3] += v.w * wei; aa[i4 * 4 + 3] += v.w * wai;
        }
    }
#pragma unroll
    for (int i = 0; i < 16; i++) {
        const int n = nbase + i;
        float mv = mem[(size_t)n * W + w];
        outmem[(size_t)n * W + w] = mv * (1.0f - ae[i]) + aa[i];
    }
    __syncthreads();   // all accumulation reads of p done before overwrite
    const int b8 = t >> 5, nl = t & 31;
#pragma unroll
    for (int bi = 0; bi < 8; bi++) {
        const int b = bi * 8 + b8;
        const size_t idx = (size_t)b * N_LOC + nb + nl;
        p_buf[idx] *= invb[b];
    }
}

// ---------------------------------------------------------------------------
// Fused kernel: 512 blocks x 256 threads, 3 store-based grid barriers.
// ---------------------------------------------------------------------------
__global__ __launch_bounds__(256, 2) void ntm_fused(
        const float* cs, const float* mem, const float* wprev,
        const float* fcw, const float* fcb,
        float* raw, float* keyb, float* erase, float* addv,
        float* gate, float* shift, float* gamma, float* beta,
        float* partialS, float* partialP,
        float* p_buf, float* emem, unsigned* bars) {
    const int t = threadIdx.x;
    const int blk = blockIdx.x;
    unsigned* flags = bars;             // 512 x 16 dwords (one line per block)
    unsigned* gen = bars + 512 * 16;    // own line

    if (blk < B_SZ) {
        phaseA(blk, t, cs, fcw, fcb, raw, keyb, erase, addv, gate, shift, gamma,
               beta);
    } else {
        prefetchB(blk, t, mem);
    }
    grid_barrier(flags, gen, 1u);
    phaseB(blk, t, mem, keyb, beta, emem, partialS);
    grid_barrier(flags, gen, 2u);
    phaseC(blk, t, emem, wprev, partialS, gate, shift, gamma, p_buf, partialP);
    grid_barrier(flags, gen, 3u);
    phaseD(blk, t, mem, erase, addv, partialP, p_buf, emem);
}

// Fallback path: same phases as 4 separate kernels (no barriers needed).
__global__ __launch_bounds__(256) void kA(const float* cs, const float* fcw,
                                          const float* fcb, float* raw, float* keyb,
                                          float* erase, float* addv, float* gate,
                                          float* shift, float* gamma, float* beta) {
    if (blockIdx.x < B_SZ)
        phaseA(blockIdx.x, threadIdx.x, cs, fcw, fcb, raw, keyb, erase, addv, gate,
               shift, gamma, beta);
}
__global__ __launch_bounds__(256) void kB(const float* mem, const float* keyb,
                                          const float* beta, float* e_buf,
                                          float* partialS) {
    phaseB(blockIdx.x, threadIdx.x, mem, keyb, beta, e_buf, partialS);
}
__global__ __launch_bounds__(256) void kC(const float* e_buf, const float* wprev,
                                          const float* partialS, const float* gate,
                                          const float* shift, const float* gamma,
                                          float* p_buf, float* partialP) {
    phaseC(blockIdx.x, threadIdx.x, e_buf, wprev, partialS, gate, shift, gamma,
           p_buf, partialP);
}
__global__ __launch_bounds__(256) void kD(const float* mem, const float* erase,
                                          const float* addv, const float* partialP,
                                          float* p_buf, float* outmem) {
    phaseD(blockIdx.x, threadIdx.x, mem, erase, addv, partialP, p_buf, outmem);
}

// ---------------------------------------------------------------------------
extern "C" void kernel_launch(void* const* d_in, const int* in_sizes, int n_in,
                              void* d_out, int out_size, void* d_ws, size_t ws_size,
                              hipStream_t stream) {
    const float* cs    = (const float*)d_in[0];   // (64, 1024)
    const float* mem   = (const float*)d_in[1];   // (16384, 128)
    const float* wprev = (const float*)d_in[2];   // (64, 16384)
    const float* fcw   = (const float*)d_in[3];   // (390, 1024)
    const float* fcb   = (const float*)d_in[4];   // (390,)

    float* out = (float*)d_out;
    float* p_buf = out;                                  // (64,16384): p -> w_new
    float* emem = out + (size_t)B_SZ * N_LOC;            // e_buf, then new_memory

    float* wsf = (float*)d_ws;
    float* raw      = wsf;               // 24960
    float* keyb     = raw + 24960;       // 8192 (16B aligned)
    float* erase    = keyb + 8192;       // 8192
    float* addv     = erase + 8192;      // 8192
    float* gate     = addv + 8192;       // 64
    float* shift    = gate + 64;         // 192
    float* gamma    = shift + 192;       // 64
    float* beta     = gamma + 64;        // 64
    float* partialS = beta + 64;         // 64*512 (16B aligned)
    float* partialP = partialS + 32768;  // 64*8 = 512
    unsigned* bars  = (unsigned*)(partialP + 512);   // 512 lines + gen line

    const size_t barsBytes = (512 * 16 + 16) * sizeof(unsigned);
    hipMemsetAsync(bars, 0, barsBytes, stream);

    void* args[] = {
        (void*)&cs, (void*)&mem, (void*)&wprev, (void*)&fcw, (void*)&fcb,
        (void*)&raw, (void*)&keyb, (void*)&erase, (void*)&addv,
        (void*)&gate, (void*)&shift, (void*)&gamma, (void*)&beta,
        (void*)&partialS, (void*)&partialP, (void*)&p_buf, (void*)&emem,
        (void*)&bars
    };
    dim3 grid(NBLK), block(256);
    hipError_t err = hipLaunchCooperativeKernel((const void*)ntm_fused, grid, block,
                                                args, 0, stream);
    if (err != hipSuccess) {
        // Fallback: 4 conventional launches with identical semantics.
        kA<<<64, 256, 0, stream>>>(cs, fcw, fcb, raw, keyb, erase, addv, gate,
                                   shift, gamma, beta);
        kB<<<512, 256, 0, stream>>>(mem, keyb, beta, emem, partialS);
        kC<<<512, 256, 0, stream>>>(emem, wprev, partialS, gate, shift, gamma,
                                    p_buf, partialP);
        kD<<<512, 256, 0, stream>>>(mem, erase, addv, partialP, p_buf, emem);
    }
}

// Round 8
// 121.976 us; speedup vs baseline: 4.8346x; 1.6766x over previous
//
#include <hip/hip_runtime.h>
#include <math.h>

#define N_LOC 16384
#define W 128
#define B_SZ 64
#define TOTAL_OUT 390   // 3*W + 6

__device__ __forceinline__ float dot4(float4 a, float4 b) {
    return a.x * b.x + a.y * b.y + a.z * b.z + a.w * b.w;
}
__device__ __forceinline__ float softplus_f(float x) {
    return fmaxf(x, 0.0f) + log1pf(expf(-fabsf(x)));
}
__device__ __forceinline__ float wave_reduce_sum(float v) {
#pragma unroll
    for (int off = 32; off >= 1; off >>= 1) v += __shfl_xor(v, off);
    return v;
}

// ---------------------------------------------------------------------------
// kA (512 blocks):
//  blocks 0..63  : raw[b][:] = cs[b].fc_w.T + fc_b, then all activations.
//  blocks 64..319: rn[n] = 1/max(||mem[n]||,eps) for 64 n each (also warms
//                  L2 with the full 8 MB of mem ahead of kB).
// ---------------------------------------------------------------------------
__global__ __launch_bounds__(256) void kA(const float* __restrict__ cs,
                                          const float* __restrict__ fcw,
                                          const float* __restrict__ fcb,
                                          const float* __restrict__ mem,
                                          float* __restrict__ raw,
                                          float* __restrict__ keyb,
                                          float* __restrict__ erase,
                                          float* __restrict__ addv,
                                          float* __restrict__ gate,
                                          float* __restrict__ shift,
                                          float* __restrict__ gamma,
                                          float* __restrict__ beta_out,
                                          float* __restrict__ rn) {
    const int t = threadIdx.x;
    const int blk = blockIdx.x;

    if (blk >= B_SZ) {
        // inverse row norms: 64 rows/block, 4 threads/row, coalesced
        if (blk < 64 + 256) {
            const int row = (blk - 64) * 64 + (t >> 2);
            const int q = t & 3;
            const float4* mr = reinterpret_cast<const float4*>(mem) +
                               (size_t)row * 32 + q * 8;
            float acc = 0.0f;
#pragma unroll
            for (int j = 0; j < 8; j++) acc += dot4(mr[j], mr[j]);
            acc += __shfl_xor(acc, 1);
            acc += __shfl_xor(acc, 2);
            if (q == 0) rn[row] = 1.0f / fmaxf(sqrtf(acc), 1e-12f);
        }
        return;
    }

    __shared__ float4 cs4s[256];
    __shared__ float rA[2];
    const int b = blk;
    cs4s[t] = reinterpret_cast<const float4*>(cs)[b * 256 + t];
    __syncthreads();
    const int lane = t & 63, wv = t >> 6;
    const float4* fcw4 = reinterpret_cast<const float4*>(fcw);
    for (int o = wv; o < TOTAL_OUT; o += 4) {
        float acc = dot4(cs4s[0 * 64 + lane], fcw4[o * 256 + 0 * 64 + lane]);
        acc += dot4(cs4s[1 * 64 + lane], fcw4[o * 256 + 1 * 64 + lane]);
        acc += dot4(cs4s[2 * 64 + lane], fcw4[o * 256 + 2 * 64 + lane]);
        acc += dot4(cs4s[3 * 64 + lane], fcw4[o * 256 + 3 * 64 + lane]);
        acc = wave_reduce_sum(acc);
        if (lane == 0) raw[b * TOTAL_OUT + o] = acc + fcb[o];
    }
    __syncthreads();     // raw row b visible block-wide
    const float* rb = raw + b * TOTAL_OUT;
    float key = (t < 128) ? rb[t] : 0.0f;
    float ss = wave_reduce_sum(key * key);
    if (t == 0 || t == 64) rA[t >> 6] = ss;
    __syncthreads();
    if (t < 128) {
        float tot = rA[0] + rA[1];
        float inv = 1.0f / fmaxf(sqrtf(tot), 1e-12f);
        float beta = softplus_f(rb[W]);
        keyb[b * W + t] = beta * key * inv;
        erase[b * W + t] = 1.0f / (1.0f + expf(-rb[W + 6 + t]));
        addv[b * W + t] = tanhf(rb[2 * W + 6 + t]);
        if (t == 0) {
            gate[b] = 1.0f / (1.0f + expf(-rb[W + 1]));
            gamma[b] = softplus_f(rb[W + 5]) + 1.0f;
            beta_out[b] = beta;
            float s0 = rb[W + 2], s1 = rb[W + 3], s2 = rb[W + 4];
            float m = fmaxf(s0, fmaxf(s1, s2));
            float e0 = expf(s0 - m), e1 = expf(s1 - m), e2 = expf(s2 - m);
            float si = 1.0f / (e0 + e1 + e2);
            shift[b * 3 + 0] = e0 * si;
            shift[b * 3 + 1] = e1 * si;
            shift[b * 3 + 2] = e2 * si;
        }
    }
}

// ---------------------------------------------------------------------------
// kB (512 blocks, 32 n each): e[b][n] = exp(keyb[b].mem[n]*rn[n] - beta[b]),
// plus per-(b, 32n) partial sums. keyb broadcast from LDS (conflict-free);
// mem rows from global (L2-warm after kA).
// ---------------------------------------------------------------------------
__global__ __launch_bounds__(256) void kB(const float* __restrict__ mem,
                                          const float* __restrict__ keyb,
                                          const float* __restrict__ beta_,
                                          const float* __restrict__ rn,
                                          float* __restrict__ e_buf,
                                          float* __restrict__ partialS) {
    __shared__ float4 kb4[B_SZ][32];   // 32 KB
    const int t = threadIdx.x;
    const int blk = blockIdx.x;

    const float4* kg = reinterpret_cast<const float4*>(keyb);
    float4* kbp = &kb4[0][0];
#pragma unroll
    for (int i = 0; i < 8; i++) kbp[t + 256 * i] = kg[t + 256 * i];
    __syncthreads();

    const int nl = t & 31;
    const int n = blk * 32 + nl;
    const int bg = t >> 5;             // 0..7 -> b = bg*8 + bi
    const float4* mrow = reinterpret_cast<const float4*>(mem) + (size_t)n * 32;

    float acc[8];
#pragma unroll
    for (int i = 0; i < 8; i++) acc[i] = 0.0f;
#pragma unroll 8
    for (int k4 = 0; k4 < 32; k4++) {
        float4 mv = mrow[k4];
#pragma unroll
        for (int bi = 0; bi < 8; bi++)
            acc[bi] += dot4(kb4[bg * 8 + bi][k4], mv);
    }
    const float r = rn[n];
    float ev[8];
#pragma unroll
    for (int bi = 0; bi < 8; bi++) {
        const int b = bg * 8 + bi;
        float e = __expf(acc[bi] * r - beta_[b]);
        ev[bi] = e;
        e_buf[(size_t)b * N_LOC + n] = e;
    }
#pragma unroll
    for (int bi = 0; bi < 8; bi++) {
        float v = ev[bi];
#pragma unroll
        for (int off = 16; off >= 1; off >>= 1) v += __shfl_xor(v, off);
        ev[bi] = v;
    }
    if (nl == 0) {
#pragma unroll
        for (int bi = 0; bi < 8; bi++)
            partialS[(bg * 8 + bi) * 512 + blk] = ev[bi];
    }
}

// ---------------------------------------------------------------------------
// kC (512 blocks = 64 b x 8 chunks of 2048): S-reduce (fixed order),
// gate-mix, circular 3-tap shift (scalar halo), sharpen, write unnormalized p
// + partialP[b][8].
// ---------------------------------------------------------------------------
__global__ __launch_bounds__(256) void kC(const float* __restrict__ e_buf,
                                          const float* __restrict__ wprev,
                                          const float* __restrict__ partialS,
                                          const float* __restrict__ gate_,
                                          const float* __restrict__ shift_,
                                          const float* __restrict__ gamma_,
                                          float* __restrict__ p_buf,
                                          float* __restrict__ partialP) {
    __shared__ float rC[4];
    const int t = threadIdx.x;
    const int blk = blockIdx.x;
    const int b = blk >> 3, c = blk & 7;
    const float* ps = partialS + b * 512;
    float sv = ps[t] + ps[t + 256];
    sv = wave_reduce_sum(sv);
    if ((t & 63) == 0) rC[t >> 6] = sv;
    __syncthreads();
    const float S = rC[0] + rC[1] + rC[2] + rC[3];

    const float gate = gate_[b];
    const float ga = gate / S;
    const float og = 1.0f - gate;
    const float gm = gamma_[b];
    const float sh0 = shift_[b * 3 + 0];
    const float sh1 = shift_[b * 3 + 1];
    const float sh2 = shift_[b * 3 + 2];

    const float* erow = e_buf + (size_t)b * N_LOC;
    const float* wrow = wprev + (size_t)b * N_LOC;
    const int nb = c * 2048 + 8 * t;

    float4 e0 = *reinterpret_cast<const float4*>(erow + nb);
    float4 e1 = *reinterpret_cast<const float4*>(erow + nb + 4);
    float4 w0 = *reinterpret_cast<const float4*>(wrow + nb);
    float4 w1 = *reinterpret_cast<const float4*>(wrow + nb + 4);
    const int nm1 = (nb + N_LOC - 1) & (N_LOC - 1);
    const int np8 = (nb + 8) & (N_LOC - 1);

    float g[10];
    g[0] = ga * erow[nm1] + og * wrow[nm1];
    g[1] = ga * e0.x + og * w0.x;
    g[2] = ga * e0.y + og * w0.y;
    g[3] = ga * e0.z + og * w0.z;
    g[4] = ga * e0.w + og * w0.w;
    g[5] = ga * e1.x + og * w1.x;
    g[6] = ga * e1.y + og * w1.y;
    g[7] = ga * e1.z + og * w1.z;
    g[8] = ga * e1.w + og * w1.w;
    g[9] = ga * erow[np8] + og * wrow[np8];

    float p[8];
    float sp = 0.0f;
#pragma unroll
    for (int j = 0; j < 8; j++) {
        float x = fmaxf(sh0 * g[j] + sh1 * g[j + 1] + sh2 * g[j + 2], 1e-9f);
        p[j] = exp2f(gm * __log2f(x));
        sp += p[j];
    }
    *reinterpret_cast<float4*>(p_buf + (size_t)b * N_LOC + nb) =
        make_float4(p[0], p[1], p[2], p[3]);
    *reinterpret_cast<float4*>(p_buf + (size_t)b * N_LOC + nb + 4) =
        make_float4(p[4], p[5], p[6], p[7]);

    sp = wave_reduce_sum(sp);
    __syncthreads();
    if ((t & 63) == 0) rC[t >> 6] = sp;
    __syncthreads();
    if (t == 0) partialP[b * 8 + c] = rC[0] + rC[1] + rC[2] + rC[3];
}

// ---------------------------------------------------------------------------
// kD (512 blocks, 32 n each): invb[b] = 1/(S2+eps) (fixed order); accumulate
// erase/add outer products with invb & 1/64 folded in; memory update; then
// in-place normalize p -> w_new for this block's n-range.
// ---------------------------------------------------------------------------
__global__ __launch_bounds__(256) void kD(const float* __restrict__ mem,
                                          const float* __restrict__ erase,
                                          const float* __restrict__ addv,
                                          const float* __restrict__ partialP,
                                          float* __restrict__ p_buf,
                                          float* __restrict__ outmem) {
    __shared__ float invb[B_SZ];
    const int t = threadIdx.x;
    const int blk = blockIdx.x;
    if (t < B_SZ) {
        const float* pp = partialP + t * 8;
        float s = 0.0f;
#pragma unroll
        for (int j = 0; j < 8; j++) s += pp[j];
        invb[t] = 1.0f / (s + 1e-9f);
    }
    __syncthreads();

    const int w = t & 127;
    const int nh = t >> 7;
    const int nb = blk * 32;
    const int nbase = nb + nh * 16;

    float ae[16], aa[16];
#pragma unroll
    for (int i = 0; i < 16; i++) { ae[i] = 0.0f; aa[i] = 0.0f; }

    for (int b = 0; b < B_SZ; b++) {
        const float ib = invb[b] * (1.0f / 64.0f);
        const float wei = erase[b * W + w] * ib;
        const float wai = addv[b * W + w] * ib;
        const float4* pr4 =
            reinterpret_cast<const float4*>(p_buf + (size_t)b * N_LOC + nbase);
#pragma unroll
        for (int i4 = 0; i4 < 4; i4++) {
            float4 v = pr4[i4];
            ae[i4 * 4 + 0] += v.x * wei; aa[i4 * 4 + 0] += v.x * wai;
            ae[i4 * 4 + 1] += v.y * wei; aa[i4 * 4 + 1] += v.y * wai;
            ae[i4 * 4 + 2] += v.z * wei; aa[i4 * 4 + 2] += v.z * wai;
            ae[i4 * 4 + 3] += v.w * wei; aa[i4 * 4 + 3] += v.w * wai;
        }
    }
#pragma unroll
    for (int i = 0; i < 16; i++) {
        const int n = nbase + i;
        float mv = mem[(size_t)n * W + w];
        outmem[(size_t)n * W + w] = mv * (1.0f - ae[i]) + aa[i];
    }
    __syncthreads();   // all accumulation reads of p done before overwrite
    const int b8 = t >> 5, nl = t & 31;
#pragma unroll
    for (int bi = 0; bi < 8; bi++) {
        const int b = bi * 8 + b8;
        const size_t idx = (size_t)b * N_LOC + nb + nl;
        p_buf[idx] *= invb[b];
    }
}

// ---------------------------------------------------------------------------
extern "C" void kernel_launch(void* const* d_in, const int* in_sizes, int n_in,
                              void* d_out, int out_size, void* d_ws, size_t ws_size,
                              hipStream_t stream) {
    const float* cs    = (const float*)d_in[0];   // (64, 1024)
    const float* mem   = (const float*)d_in[1];   // (16384, 128)
    const float* wprev = (const float*)d_in[2];   // (64, 16384)
    const float* fcw   = (const float*)d_in[3];   // (390, 1024)
    const float* fcb   = (const float*)d_in[4];   // (390,)

    float* out = (float*)d_out;
    float* p_buf = out;                                  // (64,16384): p -> w_new
    float* emem = out + (size_t)B_SZ * N_LOC;            // e_buf, then new_memory

    float* wsf = (float*)d_ws;
    float* raw      = wsf;               // 24960
    float* keyb     = raw + 24960;       // 8192 (16B aligned)
    float* erase    = keyb + 8192;       // 8192
    float* addv     = erase + 8192;      // 8192
    float* gate     = addv + 8192;       // 64
    float* shift    = gate + 64;         // 192
    float* gamma    = shift + 192;       // 64
    float* beta     = gamma + 64;        // 64
    float* partialS = beta + 64;         // 64*512 = 32768 (16B aligned)
    float* partialP = partialS + 32768;  // 64*8 = 512
    float* rn       = partialP + 512;    // 16384

    kA<<<512, 256, 0, stream>>>(cs, fcw, fcb, mem, raw, keyb, erase, addv,
                                gate, shift, gamma, beta, rn);
    kB<<<512, 256, 0, stream>>>(mem, keyb, beta, rn, emem, partialS);
    kC<<<512, 256, 0, stream>>>(emem, wprev, partialS, gate, shift, gamma,
                                p_buf, partialP);
    kD<<<512, 256, 0, stream>>>(mem, erase, addv, partialP, p_buf, emem);
}

// Round 9
// 77.898 us; speedup vs baseline: 7.5702x; 1.5658x over previous
//
#include <hip/hip_runtime.h>
#include <math.h>

#define N_LOC 16384
#define W 128
#define B_SZ 64
#define TOTAL_OUT 390   // 3*W + 6

__device__ __forceinline__ float dot4(float4 a, float4 b) {
    return a.x * b.x + a.y * b.y + a.z * b.z + a.w * b.w;
}
__device__ __forceinline__ float softplus_f(float x) {
    return fmaxf(x, 0.0f) + log1pf(expf(-fabsf(x)));
}
__device__ __forceinline__ float sigmoid_f(float x) {
    return 1.0f / (1.0f + expf(-x));
}
__device__ __forceinline__ float wave_reduce_sum(float v) {
#pragma unroll
    for (int off = 32; off >= 1; off >>= 1) v += __shfl_xor(v, off);
    return v;
}

// ---------------------------------------------------------------------------
// kA (360 blocks):
//  blocks 0..103  : FC GEMM, R4 geometry: oc=blk%13 (30 outputs), btile=blk/13
//                   (8 b). 8 cs rows in LDS; per wave: ~8 o's x 8 b-accums
//                   sharing each fcw row load (ILP against L2 latency).
//  blocks 104..359: rn[n] = 1/max(||mem[n]||,eps), 64 rows each; also warms
//                   L2 with all 8 MB of mem ahead of kB.
// ---------------------------------------------------------------------------
__global__ __launch_bounds__(256) void kA(const float* __restrict__ cs,
                                          const float* __restrict__ fcw,
                                          const float* __restrict__ fcb,
                                          const float* __restrict__ mem,
                                          float* __restrict__ raw,
                                          float* __restrict__ rn) {
    const int t = threadIdx.x;
    const int blk = blockIdx.x;

    if (blk >= 104) {
        const int row = (blk - 104) * 64 + (t >> 2);
        const int q = t & 3;
        const float4* mr = reinterpret_cast<const float4*>(mem) +
                           (size_t)row * 32 + q * 8;
        float acc = 0.0f;
#pragma unroll
        for (int j = 0; j < 8; j++) acc += dot4(mr[j], mr[j]);
        acc += __shfl_xor(acc, 1);
        acc += __shfl_xor(acc, 2);
        if (q == 0) rn[row] = 1.0f / fmaxf(sqrtf(acc), 1e-12f);
        return;
    }

    __shared__ float4 cs4[8][256];
    const int oc = blk % 13;        // 30 outputs each
    const int btile = blk / 13;     // 8 b each

    const float4* csg = reinterpret_cast<const float4*>(cs);
#pragma unroll
    for (int i = 0; i < 8; i++) {
        int f4 = t + 256 * i;
        int row = f4 >> 8;
        int col = f4 & 255;
        cs4[row][col] = csg[(btile * 8 + row) * 256 + col];
    }
    __syncthreads();

    const int lane = t & 63;
    const int wv = t >> 6;
    const float4* fcw4 = reinterpret_cast<const float4*>(fcw);

    for (int ol = wv; ol < 30; ol += 4) {
        const int o = oc * 30 + ol;
        float4 r0 = fcw4[o * 256 + 0 * 64 + lane];
        float4 r1 = fcw4[o * 256 + 1 * 64 + lane];
        float4 r2 = fcw4[o * 256 + 2 * 64 + lane];
        float4 r3 = fcw4[o * 256 + 3 * 64 + lane];
#pragma unroll
        for (int b = 0; b < 8; b++) {
            float acc = dot4(cs4[b][0 * 64 + lane], r0);
            acc += dot4(cs4[b][1 * 64 + lane], r1);
            acc += dot4(cs4[b][2 * 64 + lane], r2);
            acc += dot4(cs4[b][3 * 64 + lane], r3);
            acc = wave_reduce_sum(acc);
            if (lane == 0) {
                raw[(btile * 8 + b) * TOTAL_OUT + o] = acc + fcb[o];
            }
        }
    }
}

// ---------------------------------------------------------------------------
// kB (512 blocks, 32 n each): prologue builds kb4[b][k] = beta*key/||key||
// directly in LDS from raw (thread = (b, quarter-row)); then
// e[b][n] = exp(dot(kb4[b], mem[n]) * rn[n] - beta[b]) + per-(b,32n) partials.
// ---------------------------------------------------------------------------
__global__ __launch_bounds__(256) void kB(const float* __restrict__ mem,
                                          const float* __restrict__ raw,
                                          const float* __restrict__ rn,
                                          float* __restrict__ e_buf,
                                          float* __restrict__ partialS) {
    __shared__ float4 kb4[B_SZ][32];   // 32 KB
    __shared__ float betaS[B_SZ];
    const int t = threadIdx.x;
    const int blk = blockIdx.x;

    {   // build scaled key fragments: b = t>>2, 32 key elems per thread
        const int b = t >> 2;
        const int q = t & 3;
        const float* rb = raw + b * TOTAL_OUT;
        const float2* rk = reinterpret_cast<const float2*>(rb) + q * 16;
        float2 v[16];
        float ss = 0.0f;
#pragma unroll
        for (int j = 0; j < 16; j++) {
            v[j] = rk[j];
            ss += v[j].x * v[j].x + v[j].y * v[j].y;
        }
        ss += __shfl_xor(ss, 1);
        ss += __shfl_xor(ss, 2);
        const float beta = softplus_f(rb[W]);
        const float scale = beta / fmaxf(sqrtf(ss), 1e-12f);
        if (q == 0) betaS[b] = beta;
#pragma unroll
        for (int jj = 0; jj < 8; jj++) {
            kb4[b][q * 8 + jj] = make_float4(v[2 * jj].x * scale,
                                             v[2 * jj].y * scale,
                                             v[2 * jj + 1].x * scale,
                                             v[2 * jj + 1].y * scale);
        }
    }
    __syncthreads();

    const int nl = t & 31;
    const int n = blk * 32 + nl;
    const int bg = t >> 5;             // 0..7 -> b = bg*8 + bi
    const float4* mrow = reinterpret_cast<const float4*>(mem) + (size_t)n * 32;

    float acc[8];
#pragma unroll
    for (int i = 0; i < 8; i++) acc[i] = 0.0f;
#pragma unroll 8
    for (int k4 = 0; k4 < 32; k4++) {
        float4 mv = mrow[k4];
#pragma unroll
        for (int bi = 0; bi < 8; bi++)
            acc[bi] += dot4(kb4[bg * 8 + bi][k4], mv);
    }
    const float r = rn[n];
    float ev[8];
#pragma unroll
    for (int bi = 0; bi < 8; bi++) {
        const int b = bg * 8 + bi;
        float e = __expf(acc[bi] * r - betaS[b]);
        ev[bi] = e;
        e_buf[(size_t)b * N_LOC + n] = e;
    }
#pragma unroll
    for (int bi = 0; bi < 8; bi++) {
        float v = ev[bi];
#pragma unroll
        for (int off = 16; off >= 1; off >>= 1) v += __shfl_xor(v, off);
        ev[bi] = v;
    }
    if (nl == 0) {
#pragma unroll
        for (int bi = 0; bi < 8; bi++)
            partialS[(bg * 8 + bi) * 512 + blk] = ev[bi];
    }
}

// ---------------------------------------------------------------------------
// kC (512 blocks = 64 b x 8 chunks of 2048): prologue computes this b's
// gate/gamma/shift from raw; S-reduce (fixed order); gate-mix; circular 3-tap
// shift; sharpen; write unnormalized p + partialP[b][8]. c==0 blocks also
// emit erase/addv for kD.
// ---------------------------------------------------------------------------
__global__ __launch_bounds__(256) void kC(const float* __restrict__ e_buf,
                                          const float* __restrict__ wprev,
                                          const float* __restrict__ raw,
                                          const float* __restrict__ partialS,
                                          float* __restrict__ p_buf,
                                          float* __restrict__ partialP,
                                          float* __restrict__ erase,
                                          float* __restrict__ addv) {
    __shared__ float rC[4];
    __shared__ float cpar[5];   // gate, gamma, sh0, sh1, sh2
    const int t = threadIdx.x;
    const int blk = blockIdx.x;
    const int b = blk >> 3, c = blk & 7;
    const float* rb = raw + b * TOTAL_OUT;

    const float* ps = partialS + b * 512;
    float sv = ps[t] + ps[t + 256];
    sv = wave_reduce_sum(sv);
    if ((t & 63) == 0) rC[t >> 6] = sv;
    if (t == 0) {
        cpar[0] = sigmoid_f(rb[W + 1]);
        cpar[1] = softplus_f(rb[W + 5]) + 1.0f;
        float s0 = rb[W + 2], s1 = rb[W + 3], s2 = rb[W + 4];
        float m = fmaxf(s0, fmaxf(s1, s2));
        float e0 = expf(s0 - m), e1 = expf(s1 - m), e2 = expf(s2 - m);
        float si = 1.0f / (e0 + e1 + e2);
        cpar[2] = e0 * si;
        cpar[3] = e1 * si;
        cpar[4] = e2 * si;
    }
    __syncthreads();
    const float S = rC[0] + rC[1] + rC[2] + rC[3];

    const float gate = cpar[0];
    const float ga = gate / S;
    const float og = 1.0f - gate;
    const float gm = cpar[1];
    const float sh0 = cpar[2];
    const float sh1 = cpar[3];
    const float sh2 = cpar[4];

    if (c == 0) {   // erase/add activations for kD (1 elem/thread)
        if (t < 128) erase[b * W + t] = sigmoid_f(rb[W + 6 + t]);
        else         addv[b * W + (t - 128)] = tanhf(rb[2 * W + 6 + (t - 128)]);
    }

    const float* erow = e_buf + (size_t)b * N_LOC;
    const float* wrow = wprev + (size_t)b * N_LOC;
    const int nb = c * 2048 + 8 * t;

    float4 e0v = *reinterpret_cast<const float4*>(erow + nb);
    float4 e1v = *reinterpret_cast<const float4*>(erow + nb + 4);
    float4 w0 = *reinterpret_cast<const float4*>(wrow + nb);
    float4 w1 = *reinterpret_cast<const float4*>(wrow + nb + 4);
    const int nm1 = (nb + N_LOC - 1) & (N_LOC - 1);
    const int np8 = (nb + 8) & (N_LOC - 1);

    float g[10];
    g[0] = ga * erow[nm1] + og * wrow[nm1];
    g[1] = ga * e0v.x + og * w0.x;
    g[2] = ga * e0v.y + og * w0.y;
    g[3] = ga * e0v.z + og * w0.z;
    g[4] = ga * e0v.w + og * w0.w;
    g[5] = ga * e1v.x + og * w1.x;
    g[6] = ga * e1v.y + og * w1.y;
    g[7] = ga * e1v.z + og * w1.z;
    g[8] = ga * e1v.w + og * w1.w;
    g[9] = ga * erow[np8] + og * wrow[np8];

    float p[8];
    float sp = 0.0f;
#pragma unroll
    for (int j = 0; j < 8; j++) {
        float x = fmaxf(sh0 * g[j] + sh1 * g[j + 1] + sh2 * g[j + 2], 1e-9f);
        p[j] = exp2f(gm * __log2f(x));
        sp += p[j];
    }
    *reinterpret_cast<float4*>(p_buf + (size_t)b * N_LOC + nb) =
        make_float4(p[0], p[1], p[2], p[3]);
    *reinterpret_cast<float4*>(p_buf + (size_t)b * N_LOC + nb + 4) =
        make_float4(p[4], p[5], p[6], p[7]);

    sp = wave_reduce_sum(sp);
    __syncthreads();
    if ((t & 63) == 0) rC[t >> 6] = sp;
    __syncthreads();
    if (t == 0) partialP[b * 8 + c] = rC[0] + rC[1] + rC[2] + rC[3];
}

// ---------------------------------------------------------------------------
// kD (512 blocks, 32 n each): invb[b] = 1/(S2+eps) (fixed order); accumulate
// erase/add outer products with invb & 1/64 folded in; memory update; then
// in-place normalize p -> w_new for this block's n-range.
// ---------------------------------------------------------------------------
__global__ __launch_bounds__(256) void kD(const float* __restrict__ mem,
                                          const float* __restrict__ erase,
                                          const float* __restrict__ addv,
                                          const float* __restrict__ partialP,
                                          float* __restrict__ p_buf,
                                          float* __restrict__ outmem) {
    __shared__ float invb[B_SZ];
    const int t = threadIdx.x;
    const int blk = blockIdx.x;
    if (t < B_SZ) {
        const float* pp = partialP + t * 8;
        float s = 0.0f;
#pragma unroll
        for (int j = 0; j < 8; j++) s += pp[j];
        invb[t] = 1.0f / (s + 1e-9f);
    }
    __syncthreads();

    const int w = t & 127;
    const int nh = t >> 7;
    const int nb = blk * 32;
    const int nbase = nb + nh * 16;

    float ae[16], aa[16];
#pragma unroll
    for (int i = 0; i < 16; i++) { ae[i] = 0.0f; aa[i] = 0.0f; }

    for (int b = 0; b < B_SZ; b++) {
        const float ib = invb[b] * (1.0f / 64.0f);
        const float wei = erase[b * W + w] * ib;
        const float wai = addv[b * W + w] * ib;
        const float4* pr4 =
            reinterpret_cast<const float4*>(p_buf + (size_t)b * N_LOC + nbase);
#pragma unroll
        for (int i4 = 0; i4 < 4; i4++) {
            float4 v = pr4[i4];
            ae[i4 * 4 + 0] += v.x * wei; aa[i4 * 4 + 0] += v.x * wai;
            ae[i4 * 4 + 1] += v.y * wei; aa[i4 * 4 + 1] += v.y * wai;
            ae[i4 * 4 + 2] += v.z * wei; aa[i4 * 4 + 2] += v.z * wai;
            ae[i4 * 4 + 3] += v.w * wei; aa[i4 * 4 + 3] += v.w * wai;
        }
    }
#pragma unroll
    for (int i = 0; i < 16; i++) {
        const int n = nbase + i;
        float mv = mem[(size_t)n * W + w];
        outmem[(size_t)n * W + w] = mv * (1.0f - ae[i]) + aa[i];
    }
    __syncthreads();   // all accumulation reads of p done before overwrite
    const int b8 = t >> 5, nl = t & 31;
#pragma unroll
    for (int bi = 0; bi < 8; bi++) {
        const int b = bi * 8 + b8;
        const size_t idx = (size_t)b * N_LOC + nb + nl;
        p_buf[idx] *= invb[b];
    }
}

// ---------------------------------------------------------------------------
extern "C" void kernel_launch(void* const* d_in, const int* in_sizes, int n_in,
                              void* d_out, int out_size, void* d_ws, size_t ws_size,
                              hipStream_t stream) {
    const float* cs    = (const float*)d_in[0];   // (64, 1024)
    const float* mem   = (const float*)d_in[1];   // (16384, 128)
    const float* wprev = (const float*)d_in[2];   // (64, 16384)
    const float* fcw   = (const float*)d_in[3];   // (390, 1024)
    const float* fcb   = (const float*)d_in[4];   // (390,)

    float* out = (float*)d_out;
    float* p_buf = out;                                  // (64,16384): p -> w_new
    float* emem = out + (size_t)B_SZ * N_LOC;            // e_buf, then new_memory

    float* wsf = (float*)d_ws;
    float* raw      = wsf;               // 24960 floats
    float* erase    = raw + 24960;       // 8192
    float* addv     = erase + 8192;      // 8192
    float* partialS = addv + 8192;       // 64*512 = 32768
    float* partialP = partialS + 32768;  // 64*8 = 512
    float* rn       = partialP + 512;    // 16384

    kA<<<360, 256, 0, stream>>>(cs, fcw, fcb, mem, raw, rn);
    kB<<<512, 256, 0, stream>>>(mem, raw, rn, emem, partialS);
    kC<<<512, 256, 0, stream>>>(emem, wprev, raw, partialS, p_buf, partialP,
                                erase, addv);
    kD<<<512, 256, 0, stream>>>(mem, erase, addv, partialP, p_buf, emem);
}

// Round 11
// 68.907 us; speedup vs baseline: 8.5579x; 1.1305x over previous
//
#include <hip/hip_runtime.h>
#include <math.h>

#define N_LOC 16384
#define W 128
#define B_SZ 64
#define TOTAL_OUT 390   // 3*W + 6

__device__ __forceinline__ float dot4(float4 a, float4 b) {
    return a.x * b.x + a.y * b.y + a.z * b.z + a.w * b.w;
}
__device__ __forceinline__ float softplus_f(float x) {
    return fmaxf(x, 0.0f) + log1pf(expf(-fabsf(x)));
}
__device__ __forceinline__ float sigmoid_f(float x) {
    return 1.0f / (1.0f + expf(-x));
}
__device__ __forceinline__ float wave_reduce_sum(float v) {
#pragma unroll
    for (int off = 32; off >= 1; off >>= 1) v += __shfl_xor(v, off);
    return v;
}

// ---------------------------------------------------------------------------
// kA (208 blocks): FC GEMM only. oc = blk%26 (15 outputs), btile = blk/26
// (8 b each). 8 cs rows staged in LDS; per wave ~4 o's x 8 b-accumulators
// sharing each fcw row load (ILP against the cold-HBM fcw fetch).
// ---------------------------------------------------------------------------
__global__ __launch_bounds__(256) void kA(const float* __restrict__ cs,
                                          const float* __restrict__ fcw,
                                          const float* __restrict__ fcb,
                                          float* __restrict__ raw) {
    __shared__ float4 cs4[8][256];
    const int t = threadIdx.x;
    const int blk = blockIdx.x;
    const int oc = blk % 26;        // 15 outputs each
    const int btile = blk / 26;     // 8 b each

    const float4* csg = reinterpret_cast<const float4*>(cs);
#pragma unroll
    for (int i = 0; i < 8; i++) {
        int f4 = t + 256 * i;
        int row = f4 >> 8;
        int col = f4 & 255;
        cs4[row][col] = csg[(btile * 8 + row) * 256 + col];
    }
    __syncthreads();

    const int lane = t & 63;
    const int wv = t >> 6;
    const float4* fcw4 = reinterpret_cast<const float4*>(fcw);

    for (int ol = wv; ol < 15; ol += 4) {
        const int o = oc * 15 + ol;
        float4 r0 = fcw4[o * 256 + 0 * 64 + lane];
        float4 r1 = fcw4[o * 256 + 1 * 64 + lane];
        float4 r2 = fcw4[o * 256 + 2 * 64 + lane];
        float4 r3 = fcw4[o * 256 + 3 * 64 + lane];
#pragma unroll
        for (int b = 0; b < 8; b++) {
            float acc = dot4(cs4[b][0 * 64 + lane], r0);
            acc += dot4(cs4[b][1 * 64 + lane], r1);
            acc += dot4(cs4[b][2 * 64 + lane], r2);
            acc += dot4(cs4[b][3 * 64 + lane], r3);
            acc = wave_reduce_sum(acc);
            if (lane == 0) {
                raw[(btile * 8 + b) * TOTAL_OUT + o] = acc + fcb[o];
            }
        }
    }
}

// ---------------------------------------------------------------------------
// kB (512 blocks, 32 n each): prologue builds kb4[b][k] = beta*key/||key||
// directly in LDS from raw; inner loop computes dot products against mem
// rows with the row norm fused (registers already loaded -> free); emits
// e[b][n] = exp(cos*beta - beta) + per-(b,32n) partial sums.
// ---------------------------------------------------------------------------
__global__ __launch_bounds__(256) void kB(const float* __restrict__ mem,
                                          const float* __restrict__ raw,
                                          float* __restrict__ e_buf,
                                          float* __restrict__ partialS) {
    __shared__ float4 kb4[B_SZ][32];   // 32 KB
    __shared__ float betaS[B_SZ];
    const int t = threadIdx.x;
    const int blk = blockIdx.x;

    {   // build scaled key fragments: b = t>>2, 32 key elems per thread
        const int b = t >> 2;
        const int q = t & 3;
        const float* rb = raw + b * TOTAL_OUT;
        const float2* rk = reinterpret_cast<const float2*>(rb) + q * 16;
        float2 v[16];
        float ss = 0.0f;
#pragma unroll
        for (int j = 0; j < 16; j++) {
            v[j] = rk[j];
            ss += v[j].x * v[j].x + v[j].y * v[j].y;
        }
        ss += __shfl_xor(ss, 1);
        ss += __shfl_xor(ss, 2);
        const float beta = softplus_f(rb[W]);
        const float scale = beta / fmaxf(sqrtf(ss), 1e-12f);
        if (q == 0) betaS[b] = beta;
#pragma unroll
        for (int jj = 0; jj < 8; jj++) {
            kb4[b][q * 8 + jj] = make_float4(v[2 * jj].x * scale,
                                             v[2 * jj].y * scale,
                                             v[2 * jj + 1].x * scale,
                                             v[2 * jj + 1].y * scale);
        }
    }
    __syncthreads();

    const int nl = t & 31;
    const int n = blk * 32 + nl;
    const int bg = t >> 5;             // 0..7 -> b = bg*8 + bi
    const float4* mrow = reinterpret_cast<const float4*>(mem) + (size_t)n * 32;

    float acc[8];
#pragma unroll
    for (int i = 0; i < 8; i++) acc[i] = 0.0f;
    float nrm = 0.0f;
#pragma unroll 8
    for (int k4 = 0; k4 < 32; k4++) {
        float4 mv = mrow[k4];
        nrm += dot4(mv, mv);
#pragma unroll
        for (int bi = 0; bi < 8; bi++)
            acc[bi] += dot4(kb4[bg * 8 + bi][k4], mv);
    }
    const float r = 1.0f / fmaxf(sqrtf(nrm), 1e-12f);
    float ev[8];
#pragma unroll
    for (int bi = 0; bi < 8; bi++) {
        const int b = bg * 8 + bi;
        float e = __expf(acc[bi] * r - betaS[b]);
        ev[bi] = e;
        e_buf[(size_t)b * N_LOC + n] = e;
    }
#pragma unroll
    for (int bi = 0; bi < 8; bi++) {
        float v = ev[bi];
#pragma unroll
        for (int off = 16; off >= 1; off >>= 1) v += __shfl_xor(v, off);
        ev[bi] = v;
    }
    if (nl == 0) {
#pragma unroll
        for (int bi = 0; bi < 8; bi++)
            partialS[(bg * 8 + bi) * 512 + blk] = ev[bi];
    }
}

// ---------------------------------------------------------------------------
// kC (512 blocks = 64 b x 8 chunks of 2048): per-b scalars from raw;
// S-reduce (fixed order); gate-mix; circular 3-tap shift (scalar halo);
// sharpen; write unnormalized p + partialP[b][8]; c==0 blocks also emit
// erase/addv activations for kD.
// ---------------------------------------------------------------------------
__global__ __launch_bounds__(256) void kC(const float* __restrict__ e_buf,
                                          const float* __restrict__ wprev,
                                          const float* __restrict__ raw,
                                          const float* __restrict__ partialS,
                                          float* __restrict__ p_buf,
                                          float* __restrict__ partialP,
                                          float* __restrict__ erase,
                                          float* __restrict__ addv) {
    __shared__ float rC[4];
    __shared__ float cpar[5];   // gate, gamma, sh0, sh1, sh2
    const int t = threadIdx.x;
    const int blk = blockIdx.x;
    const int b = blk >> 3, c = blk & 7;
    const float* rb = raw + b * TOTAL_OUT;

    const float* ps = partialS + b * 512;
    float sv = ps[t] + ps[t + 256];
    sv = wave_reduce_sum(sv);
    if ((t & 63) == 0) rC[t >> 6] = sv;
    if (t == 0) {
        cpar[0] = sigmoid_f(rb[W + 1]);
        cpar[1] = softplus_f(rb[W + 5]) + 1.0f;
        float s0 = rb[W + 2], s1 = rb[W + 3], s2 = rb[W + 4];
        float m = fmaxf(s0, fmaxf(s1, s2));
        float e0 = expf(s0 - m), e1 = expf(s1 - m), e2 = expf(s2 - m);
        float si = 1.0f / (e0 + e1 + e2);
        cpar[2] = e0 * si;
        cpar[3] = e1 * si;
        cpar[4] = e2 * si;
    }
    __syncthreads();
    const float S = rC[0] + rC[1] + rC[2] + rC[3];

    const float gate = cpar[0];
    const float ga = gate / S;
    const float og = 1.0f - gate;
    const float gm = cpar[1];
    const float sh0 = cpar[2];
    const float sh1 = cpar[3];
    const float sh2 = cpar[4];

    if (c == 0) {   // erase/add activations for kD (1 elem/thread)
        if (t < 128) erase[b * W + t] = sigmoid_f(rb[W + 6 + t]);
        else         addv[b * W + (t - 128)] = tanhf(rb[2 * W + 6 + (t - 128)]);
    }

    const float* erow = e_buf + (size_t)b * N_LOC;
    const float* wrow = wprev + (size_t)b * N_LOC;
    const int nb = c * 2048 + 8 * t;

    float4 e0v = *reinterpret_cast<const float4*>(erow + nb);
    float4 e1v = *reinterpret_cast<const float4*>(erow + nb + 4);
    float4 w0 = *reinterpret_cast<const float4*>(wrow + nb);
    float4 w1 = *reinterpret_cast<const float4*>(wrow + nb + 4);
    const int nm1 = (nb + N_LOC - 1) & (N_LOC - 1);
    const int np8 = (nb + 8) & (N_LOC - 1);

    float g[10];
    g[0] = ga * erow[nm1] + og * wrow[nm1];
    g[1] = ga * e0v.x + og * w0.x;
    g[2] = ga * e0v.y + og * w0.y;
    g[3] = ga * e0v.z + og * w0.z;
    g[4] = ga * e0v.w + og * w0.w;
    g[5] = ga * e1v.x + og * w1.x;
    g[6] = ga * e1v.y + og * w1.y;
    g[7] = ga * e1v.z + og * w1.z;
    g[8] = ga * e1v.w + og * w1.w;
    g[9] = ga * erow[np8] + og * wrow[np8];

    float p[8];
    float sp = 0.0f;
#pragma unroll
    for (int j = 0; j < 8; j++) {
        float x = fmaxf(sh0 * g[j] + sh1 * g[j + 1] + sh2 * g[j + 2], 1e-9f);
        p[j] = exp2f(gm * __log2f(x));
        sp += p[j];
    }
    *reinterpret_cast<float4*>(p_buf + (size_t)b * N_LOC + nb) =
        make_float4(p[0], p[1], p[2], p[3]);
    *reinterpret_cast<float4*>(p_buf + (size_t)b * N_LOC + nb + 4) =
        make_float4(p[4], p[5], p[6], p[7]);

    sp = wave_reduce_sum(sp);
    __syncthreads();
    if ((t & 63) == 0) rC[t >> 6] = sp;
    __syncthreads();
    if (t == 0) partialP[b * 8 + c] = rC[0] + rC[1] + rC[2] + rC[3];
}

// ---------------------------------------------------------------------------
// kD (512 blocks, 32 n each): invb[b] = 1/(S2+eps) (fixed order); accumulate
// erase/add outer products with invb & 1/64 folded in; memory update; then
// in-place normalize p -> w_new for this block's n-range.
// ---------------------------------------------------------------------------
__global__ __launch_bounds__(256) void kD(const float* __restrict__ mem,
                                          const float* __restrict__ erase,
                                          const float* __restrict__ addv,
                                          const float* __restrict__ partialP,
                                          float* __restrict__ p_buf,
                                          float* __restrict__ outmem) {
    __shared__ float invb[B_SZ];
    const int t = threadIdx.x;
    const int blk = blockIdx.x;
    if (t < B_SZ) {
        const float* pp = partialP + t * 8;
        float s = 0.0f;
#pragma unroll
        for (int j = 0; j < 8; j++) s += pp[j];
        invb[t] = 1.0f / (s + 1e-9f);
    }
    __syncthreads();

    const int w = t & 127;
    const int nh = t >> 7;
    const int nb = blk * 32;
    const int nbase = nb + nh * 16;

    float ae[16], aa[16];
#pragma unroll
    for (int i = 0; i < 16; i++) { ae[i] = 0.0f; aa[i] = 0.0f; }

    for (int b = 0; b < B_SZ; b++) {
        const float ib = invb[b] * (1.0f / 64.0f);
        const float wei = erase[b * W + w] * ib;
        const float wai = addv[b * W + w] * ib;
        const float4* pr4 =
            reinterpret_cast<const float4*>(p_buf + (size_t)b * N_LOC + nbase);
#pragma unroll
        for (int i4 = 0; i4 < 4; i4++) {
            float4 v = pr4[i4];
            ae[i4 * 4 + 0] += v.x * wei; aa[i4 * 4 + 0] += v.x * wai;
            ae[i4 * 4 + 1] += v.y * wei; aa[i4 * 4 + 1] += v.y * wai;
            ae[i4 * 4 + 2] += v.z * wei; aa[i4 * 4 + 2] += v.z * wai;
            ae[i4 * 4 + 3] += v.w * wei; aa[i4 * 4 + 3] += v.w * wai;
        }
    }
#pragma unroll
    for (int i = 0; i < 16; i++) {
        const int n = nbase + i;
        float mv = mem[(size_t)n * W + w];
        outmem[(size_t)n * W + w] = mv * (1.0f - ae[i]) + aa[i];
    }
    __syncthreads();   // all accumulation reads of p done before overwrite
    const int b8 = t >> 5, nl = t & 31;
#pragma unroll
    for (int bi = 0; bi < 8; bi++) {
        const int b = bi * 8 + b8;
        const size_t idx = (size_t)b * N_LOC + nb + nl;
        p_buf[idx] *= invb[b];
    }
}

// ---------------------------------------------------------------------------
extern "C" void kernel_launch(void* const* d_in, const int* in_sizes, int n_in,
                              void* d_out, int out_size, void* d_ws, size_t ws_size,
                              hipStream_t stream) {
    const float* cs    = (const float*)d_in[0];   // (64, 1024)
    const float* mem   = (const float*)d_in[1];   // (16384, 128)
    const float* wprev = (const float*)d_in[2];   // (64, 16384)
    const float* fcw   = (const float*)d_in[3];   // (390, 1024)
    const float* fcb   = (const float*)d_in[4];   // (390,)

    float* out = (float*)d_out;
    float* p_buf = out;                                  // (64,16384): p -> w_new
    float* emem = out + (size_t)B_SZ * N_LOC;            // e_buf, then new_memory

    float* wsf = (float*)d_ws;
    float* raw      = wsf;               // 24960 floats
    float* erase    = raw + 24960;       // 8192
    float* addv     = erase + 8192;      // 8192
    float* partialS = addv + 8192;       // 64*512 = 32768
    float* partialP = partialS + 32768;  // 64*8 = 512

    kA<<<208, 256, 0, stream>>>(cs, fcw, fcb, raw);
    kB<<<512, 256, 0, stream>>>(mem, raw, emem, partialS);
    kC<<<512, 256, 0, stream>>>(emem, wprev, raw, partialS, p_buf, partialP,
                                erase, addv);
    kD<<<512, 256, 0, stream>>>(mem, erase, addv, partialP, p_buf, emem);
}